// Round 5
// baseline (155.001 us; speedup 1.0000x reference)
//
#include <hip/hip_runtime.h>
#include <math.h>

// Shapes: B=128, S=192, N=32, PREC_DIM=2, E=64, H=4, D=16, FF=256, M=24576.
//
// Algebra: pv_n = Ue^T pvec_n, pvec=(x,y,1), Ue=[We0;We1;be] (3x64).
// energy[h][n] = qvec^T M_h pvec_n,  M_h = Te_h Ke_h^T (3x3),
//   Te_h = Ue_h Wq, Ke_h = Ue_h Wk (3x16 each).
// ao[e] = sum_h ctx_h . G_h[:,e] + bo,  G_h = (Ue_h Wv) Wo_h (3x64),
//   ctx_h = (sum_n w x, sum_n w y, 1),  w = softmax weights.
namespace {

constexpr int S_  = 192;
constexpr int TPW = 4;   // tokens per wave
constexpr int WVB = 4;   // waves per block; 16 tokens/block; grid = 1536 (6 blocks/CU)

// Per-wave LDS visibility: drain the LDS queue (in-order per-wave processing).
__device__ __forceinline__ void wave_fence() {
  asm volatile("s_waitcnt lgkmcnt(0)" ::: "memory");
}

__launch_bounds__(256, 6)
__global__ void prec_fused(
    const float* __restrict__ prec,  const int*   __restrict__ tmask,
    const float* __restrict__ We,    const float* __restrict__ be,
    const float* __restrict__ Wq,    const float* __restrict__ Wk,
    const float* __restrict__ Wv,    const float* __restrict__ Wo,
    const float* __restrict__ bo,    const float* __restrict__ g1,
    const float* __restrict__ bb1,   const float* __restrict__ W1,
    const float* __restrict__ b1,    const float* __restrict__ W2,
    const float* __restrict__ b2,    const float* __restrict__ g2,
    const float* __restrict__ bb2,   float* __restrict__ out)
{
  // sh: prologue scratch (flat, block-shared), then per-wave h1[4][256] in phase B
  __shared__ __align__(16) float sh[WVB][1040];
  __shared__ __align__(16) float sxoh[WVB][TPW][64];   // LN1 output x

  const int tid  = threadIdx.x;
  const int wv   = tid >> 6;
  const int lane = tid & 63;
  const int u    = lane >> 5;   // half index (heads 2u,2u+1)
  const int n    = lane & 31;   // precedence slot
  const int tokbase = (blockIdx.x * WVB + wv) * TPW;
  const int bidx0 = tokbase / S_;              // batch: constant per wave (192%16==0)
  const int srow0 = tokbase - bidx0 * S_;

  float* __restrict__ sc = &sh[0][0];
  // sc layout (floats): 0:Ue0[64] 64:Ue1[64] 128:be[64] 192:Wq[256] 448:Wk[256]
  //  704:Wv[256] 960:Te[192] 1152:Ke[192] 1344:Ve[192] 1536:M[36] 1600:G[768]

  // ---- P1: stage small weights (block-cooperative) ----
  if (tid < 64) { sc[tid] = We[tid]; sc[64 + tid] = We[64 + tid]; sc[128 + tid] = be[tid]; }
  sc[192 + tid] = Wq[tid];
  sc[448 + tid] = Wk[tid];
  sc[704 + tid] = Wv[tid];
  __syncthreads();

  // ---- P2: Te/Ke/Ve = Ue_h @ {Wq,Wk,Wv}  (wave sel handles one matrix) ----
  {
    const int sel = tid >> 6;              // 0:T 1:K 2:V; wave 3 idle
    if (sel < 3) {
      const int h = (tid >> 4) & 3, c = tid & 15;
      const float* Wm = sc + 192 + sel * 256;
      float a0 = 0.f, a1 = 0.f, a2 = 0.f;
      #pragma unroll
      for (int dp = 0; dp < 16; ++dp) {
        const float w = Wm[dp * 16 + c];
        a0 = fmaf(sc[h * 16 + dp],        w, a0);
        a1 = fmaf(sc[64 + h * 16 + dp],   w, a1);
        a2 = fmaf(sc[128 + h * 16 + dp],  w, a2);
      }
      const int base = 960 + sel * 192 + h * 48 + c;   // (h*3+a)*16+c
      sc[base] = a0; sc[base + 16] = a1; sc[base + 32] = a2;
    }
  }
  __syncthreads();

  // ---- P3: M (36 vals, lanes 0-35 of wave 0) + G (wave h computes head h) ----
  if (tid < 36) {
    const int h = tid / 9, ab = tid - h * 9, a = ab / 3, b = ab - a * 3;
    const float* Tp = sc + 960  + h * 48 + a * 16;
    const float* Kp = sc + 1152 + h * 48 + b * 16;
    float s = 0.f;
    #pragma unroll
    for (int c = 0; c < 16; ++c) s = fmaf(Tp[c], Kp[c], s);
    sc[1536 + tid] = s;
  }
  {
    const int e = tid & 63, h = tid >> 6;
    const float* Vp = sc + 1344 + h * 48;
    float q0 = 0.f, q1 = 0.f, q2 = 0.f;
    #pragma unroll
    for (int dp = 0; dp < 16; ++dp) {
      const float wo = Wo[(h * 16 + dp) * 64 + e];
      q0 = fmaf(Vp[dp],      wo, q0);
      q1 = fmaf(Vp[16 + dp], wo, q1);
      q2 = fmaf(Vp[32 + dp], wo, q2);
    }
    sc[1600 + (h * 3 + 0) * 64 + e] = q0;
    sc[1600 + (h * 3 + 1) * 64 + e] = q1;
    sc[1600 + (h * 3 + 2) * 64 + e] = q2;
  }
  __syncthreads();

  // ---- P4: gather per-lane invariants ----
  float m0[9], m1[9];
  #pragma unroll
  for (int i = 0; i < 9; ++i) {
    m0[i] = sc[1536 + (2 * u) * 9 + i];
    m1[i] = sc[1536 + (2 * u + 1) * 9 + i];
  }
  const int hoA = 2 * u, hoB = 2 * u + 1, htA = 2 - 2 * u, htB = 3 - 2 * u;
  float gO0[2], gO1[2], gT0[2], gT1[2];
  #pragma unroll
  for (int a = 0; a < 2; ++a) {
    gO0[a] = sc[1600 + (hoA * 3 + a) * 64 + lane];
    gO1[a] = sc[1600 + (hoB * 3 + a) * 64 + lane];
    gT0[a] = sc[1600 + (htA * 3 + a) * 64 + lane];
    gT1[a] = sc[1600 + (htB * 3 + a) * 64 + lane];
  }
  float c0 = bo[lane];
  #pragma unroll
  for (int h = 0; h < 4; ++h) c0 += sc[1600 + (h * 3 + 2) * 64 + lane];
  const float we0l = sc[lane], we1l = sc[64 + lane], bel = sc[128 + lane];
  const float g1l = g1[lane], b1l_ = bb1[lane];
  const bool masked = (tmask[bidx0 * 32 + n] == 0);
  const bool allm   = (__all((int)masked) != 0);   // wave-uniform; ref: uniform attn
  __syncthreads();   // sc fully consumed; per-wave sh[wv] overlay is now safe

  // ================= Phase A: attention + ao + LN1 (no barriers) =================
  #pragma unroll 2
  for (int p = 0; p < TPW; ++p) {
    const int m     = tokbase + p;
    const int nstar = (srow0 + p) & 31;

    const float qx = prec[(size_t)m * 64 + nstar * 2];
    const float qy = prec[(size_t)m * 64 + nstar * 2 + 1];
    const float2 pin = *(const float2*)(prec + (size_t)m * 64 + n * 2);

    // en = (cA*x + cB*y + cC)/8, c* = qvec^T M
    const float cA0 = fmaf(qy, m0[3], fmaf(qx, m0[0], m0[6]));
    const float cB0 = fmaf(qy, m0[4], fmaf(qx, m0[1], m0[7]));
    const float cC0 = fmaf(qy, m0[5], fmaf(qx, m0[2], m0[8]));
    const float cA1 = fmaf(qy, m1[3], fmaf(qx, m1[0], m1[6]));
    const float cB1 = fmaf(qy, m1[4], fmaf(qx, m1[1], m1[7]));
    const float cC1 = fmaf(qy, m1[5], fmaf(qx, m1[2], m1[8]));
    const float en0 = fmaf(pin.y, cB0, fmaf(pin.x, cA0, cC0)) * 0.125f;
    const float en1 = fmaf(pin.y, cB1, fmaf(pin.x, cA1, cC1)) * 0.125f;

    // unnormalized weights (no max-subtract: |en| << 1); allm -> uniform
    float pe0, pe1;
    if (allm) { pe0 = 1.f; pe1 = 1.f; }
    else {
      pe0 = masked ? 0.f : __expf(en0);
      pe1 = masked ? 0.f : __expf(en1);
    }

    // one merged butterfly: (pe, pe*x, pe*y) per head
    float r0 = pe0 * pin.x, r1 = pe0 * pin.y, r2 = pe0;
    float r3 = pe1 * pin.x, r4 = pe1 * pin.y, r5 = pe1;
    #pragma unroll
    for (int o = 1; o < 32; o <<= 1) {
      r0 += __shfl_xor(r0, o, 64); r1 += __shfl_xor(r1, o, 64);
      r2 += __shfl_xor(r2, o, 64); r3 += __shfl_xor(r3, o, 64);
      r4 += __shfl_xor(r4, o, 64); r5 += __shfl_xor(r5, o, 64);
    }
    const float o0 = __shfl_xor(r0, 32, 64), o1 = __shfl_xor(r1, 32, 64);
    const float o2 = __shfl_xor(r2, 32, 64), o3 = __shfl_xor(r3, 32, 64);
    const float o4 = __shfl_xor(r4, 32, 64), o5 = __shfl_xor(r5, 32, 64);
    const float i0 = __builtin_amdgcn_rcpf(r2), i1 = __builtin_amdgcn_rcpf(r5);
    const float i2 = __builtin_amdgcn_rcpf(o2), i3 = __builtin_amdgcn_rcpf(o5);

    // v = ao + residual q
    float v = c0;
    v = fmaf(fmaf(r1, gO0[1], r0 * gO0[0]), i0, v);
    v = fmaf(fmaf(r4, gO1[1], r3 * gO1[0]), i1, v);
    v = fmaf(fmaf(o1, gT0[1], o0 * gT0[0]), i2, v);
    v = fmaf(fmaf(o4, gT1[1], o3 * gT1[0]), i3, v);
    v += fmaf(qy, we1l, fmaf(qx, we0l, bel));

    // LN1 (one-pass)
    float sm = v, s2 = v * v;
    #pragma unroll
    for (int o = 1; o < 64; o <<= 1) {
      sm += __shfl_xor(sm, o, 64);
      s2 += __shfl_xor(s2, o, 64);
    }
    const float mu  = sm * (1.f / 64.f);
    const float var = s2 * (1.f / 64.f) - mu * mu;
    const float rs  = rsqrtf(var + 1e-5f);
    sxoh[wv][p][lane] = (v - mu) * rs * g1l + b1l_;
  }
  wave_fence();

  // ================= Phase B: FF + LN2 =================
  // h1 = relu(x @ W1 + b1); lane owns cols lane+64k
  float hacc[TPW][4];
  #pragma unroll
  for (int k = 0; k < 4; ++k) {
    const float bk = b1[lane + 64 * k];
    #pragma unroll
    for (int t = 0; t < TPW; ++t) hacc[t][k] = bk;
  }
  #pragma unroll 4
  for (int e4 = 0; e4 < 16; ++e4) {
    float wr[4][4];
    #pragma unroll
    for (int kk = 0; kk < 4; ++kk)
      #pragma unroll
      for (int k = 0; k < 4; ++k)
        wr[kk][k] = W1[(e4 * 4 + kk) * 256 + lane + 64 * k];
    #pragma unroll
    for (int t = 0; t < TPW; ++t) {
      const float4 xv = *(const float4*)&sxoh[wv][t][e4 * 4];
      #pragma unroll
      for (int k = 0; k < 4; ++k) {
        hacc[t][k] = fmaf(xv.x, wr[0][k], hacc[t][k]);
        hacc[t][k] = fmaf(xv.y, wr[1][k], hacc[t][k]);
        hacc[t][k] = fmaf(xv.z, wr[2][k], hacc[t][k]);
        hacc[t][k] = fmaf(xv.w, wr[3][k], hacc[t][k]);
      }
    }
  }
  float* __restrict__ h1buf = sh[wv];
  #pragma unroll
  for (int t = 0; t < TPW; ++t)
    #pragma unroll
    for (int k = 0; k < 4; ++k)
      h1buf[t * 256 + lane + 64 * k] = fmaxf(hacc[t][k], 0.f);
  wave_fence();

  // ff2 = h1 @ W2 + b2; half tg handles tokens {2tg, 2tg+1}, cols (e0,e0+1)
  const int tg = lane >> 5;
  const int e0 = (lane & 31) * 2;
  float f2a[2][2];
  {
    const float2 b2v = *(const float2*)(b2 + e0);
    f2a[0][0] = b2v.x; f2a[0][1] = b2v.y;
    f2a[1][0] = b2v.x; f2a[1][1] = b2v.y;
  }
  const float* __restrict__ hb = h1buf + tg * 2 * 256;
  #pragma unroll 8
  for (int f4 = 0; f4 < 64; ++f4) {
    const float4 hv0 = *(const float4*)(hb + f4 * 4);
    const float4 hv1 = *(const float4*)(hb + 256 + f4 * 4);
    const float2 w0 = *(const float2*)(W2 + (f4 * 4 + 0) * 64 + e0);
    const float2 w1 = *(const float2*)(W2 + (f4 * 4 + 1) * 64 + e0);
    const float2 w2 = *(const float2*)(W2 + (f4 * 4 + 2) * 64 + e0);
    const float2 w3 = *(const float2*)(W2 + (f4 * 4 + 3) * 64 + e0);
    f2a[0][0] = fmaf(hv0.x, w0.x, f2a[0][0]); f2a[0][1] = fmaf(hv0.x, w0.y, f2a[0][1]);
    f2a[0][0] = fmaf(hv0.y, w1.x, f2a[0][0]); f2a[0][1] = fmaf(hv0.y, w1.y, f2a[0][1]);
    f2a[0][0] = fmaf(hv0.z, w2.x, f2a[0][0]); f2a[0][1] = fmaf(hv0.z, w2.y, f2a[0][1]);
    f2a[0][0] = fmaf(hv0.w, w3.x, f2a[0][0]); f2a[0][1] = fmaf(hv0.w, w3.y, f2a[0][1]);
    f2a[1][0] = fmaf(hv1.x, w0.x, f2a[1][0]); f2a[1][1] = fmaf(hv1.x, w0.y, f2a[1][1]);
    f2a[1][0] = fmaf(hv1.y, w1.x, f2a[1][0]); f2a[1][1] = fmaf(hv1.y, w1.y, f2a[1][1]);
    f2a[1][0] = fmaf(hv1.z, w2.x, f2a[1][0]); f2a[1][1] = fmaf(hv1.z, w2.y, f2a[1][1]);
    f2a[1][0] = fmaf(hv1.w, w3.x, f2a[1][0]); f2a[1][1] = fmaf(hv1.w, w3.y, f2a[1][1]);
  }

  // LN2 + residual + store (32-lane half reduction)
  {
    const float2 g2v  = *(const float2*)(g2 + e0);
    const float2 bb2v = *(const float2*)(bb2 + e0);
    #pragma unroll
    for (int i = 0; i < 2; ++i) {
      const int t = tg * 2 + i;
      const float2 xv = *(const float2*)&sxoh[wv][t][e0];
      const float v0 = f2a[i][0] + xv.x;
      const float v1 = f2a[i][1] + xv.y;
      float sm = v0 + v1, s2 = v0 * v0 + v1 * v1;
      #pragma unroll
      for (int o = 1; o < 32; o <<= 1) {
        sm += __shfl_xor(sm, o, 64);
        s2 += __shfl_xor(s2, o, 64);
      }
      const float mu  = sm * (1.f / 64.f);
      const float var = s2 * (1.f / 64.f) - mu * mu;
      const float rs  = rsqrtf(var + 1e-5f);
      float2 o2;
      o2.x = (v0 - mu) * rs * g2v.x + bb2v.x;
      o2.y = (v1 - mu) * rs * g2v.y + bb2v.y;
      *(float2*)(out + (size_t)(tokbase + t) * 64 + e0) = o2;
    }
  }
}

} // namespace

extern "C" void kernel_launch(void* const* d_in, const int* in_sizes, int n_in,
                              void* d_out, int out_size, void* d_ws, size_t ws_size,
                              hipStream_t stream) {
  (void)in_sizes; (void)n_in; (void)d_ws; (void)ws_size; (void)out_size;
  const float* prec = (const float*)d_in[0];
  const int*   tm   = (const int*)  d_in[1];
  const float* We   = (const float*)d_in[2];
  const float* be   = (const float*)d_in[3];
  const float* Wq   = (const float*)d_in[4];
  const float* Wk   = (const float*)d_in[5];
  const float* Wv   = (const float*)d_in[6];
  const float* Wo   = (const float*)d_in[7];
  const float* bo   = (const float*)d_in[8];
  const float* g1   = (const float*)d_in[9];
  const float* bb1  = (const float*)d_in[10];
  const float* W1   = (const float*)d_in[11];
  const float* b1   = (const float*)d_in[12];
  const float* W2   = (const float*)d_in[13];
  const float* b2   = (const float*)d_in[14];
  const float* g2   = (const float*)d_in[15];
  const float* bb2  = (const float*)d_in[16];

  dim3 grid(1536), block(256);
  hipLaunchKernelGGL(prec_fused, grid, block, 0, stream,
                     prec, tm, We, be, Wq, Wk, Wv, Wo, bo, g1, bb1,
                     W1, b1, W2, b2, g2, bb2, (float*)d_out);
}

// Round 6
// 139.979 us; speedup vs baseline: 1.1073x; 1.1073x over previous
//
#include <hip/hip_runtime.h>
#include <math.h>

// Shapes: B=128, S=192, N=32, PREC_DIM=2, E=64, H=4, D=16, FF=256, M=24576.
//
// Algebra: pv_n = Ue^T pvec_n, pvec=(x,y,1), Ue=[We0;We1;be] (3x64).
// energy[h][n] = qvec^T M_h pvec_n,  M_h = Te_h Ke_h^T (3x3),
//   Te_h = Ue_h Wq, Ke_h = Ue_h Wk (3x16 each).
// ao[e] = sum_h ctx_h . G_h[:,e] + bo,  G_h = (Ue_h Wv) Wo_h (3x64),
//   ctx_h = (sum_n w x, sum_n w y, 1),  w = softmax weights.
namespace {

constexpr int S_  = 192;
constexpr int TPW = 8;   // tokens per wave (weight-reuse factor)
constexpr int WVB = 4;   // waves per block; 32 tokens/block; grid = 768

// Per-wave LDS visibility: drain the LDS queue (in-order per-wave processing).
__device__ __forceinline__ void wave_fence() {
  asm volatile("s_waitcnt lgkmcnt(0)" ::: "memory");
}

__launch_bounds__(256)
__attribute__((amdgpu_waves_per_eu(4, 4)))   // LDS caps at 4 waves/EU; let allocator use 128 VGPR
__global__ void prec_fused(
    const float* __restrict__ prec,  const int*   __restrict__ tmask,
    const float* __restrict__ We,    const float* __restrict__ be,
    const float* __restrict__ Wq,    const float* __restrict__ Wk,
    const float* __restrict__ Wv,    const float* __restrict__ Wo,
    const float* __restrict__ bo,    const float* __restrict__ g1,
    const float* __restrict__ bb1,   const float* __restrict__ W1,
    const float* __restrict__ b1,    const float* __restrict__ W2,
    const float* __restrict__ b2,    const float* __restrict__ g2,
    const float* __restrict__ bb2,   float* __restrict__ out)
{
  // sh: prologue scratch (flat, block-shared), then per-wave h1[8][256] in phase B
  __shared__ __align__(16) float sh[WVB][2048];
  __shared__ __align__(16) float sxoh[WVB][TPW][64];   // LN1 output x

  const int tid  = threadIdx.x;
  const int wv   = tid >> 6;
  const int lane = tid & 63;
  const int u    = lane >> 5;   // half index (heads 2u,2u+1)
  const int n    = lane & 31;   // precedence slot
  const int tokbase = (blockIdx.x * WVB + wv) * TPW;
  const int bidx0 = tokbase / S_;              // batch: constant per wave (192%32==0 per block)
  const int srow0 = tokbase - bidx0 * S_;

  float* __restrict__ sc = &sh[0][0];
  // sc layout (floats): 0:Ue0[64] 64:Ue1[64] 128:be[64] 192:Wq[256] 448:Wk[256]
  //  704:Wv[256] 960:Te[192] 1152:Ke[192] 1344:Ve[192] 1536:M[36] 1600:G[768]

  // ---- P1: stage small weights (block-cooperative) ----
  if (tid < 64) { sc[tid] = We[tid]; sc[64 + tid] = We[64 + tid]; sc[128 + tid] = be[tid]; }
  sc[192 + tid] = Wq[tid];
  sc[448 + tid] = Wk[tid];
  sc[704 + tid] = Wv[tid];
  __syncthreads();

  // ---- P2: Te/Ke/Ve = Ue_h @ {Wq,Wk,Wv} (one wave per matrix) ----
  {
    const int sel = tid >> 6;              // 0:T 1:K 2:V; wave 3 idle
    if (sel < 3) {
      const int h = (tid >> 4) & 3, c = tid & 15;
      const float* Wm = sc + 192 + sel * 256;
      float a0 = 0.f, a1 = 0.f, a2 = 0.f;
      #pragma unroll
      for (int dp = 0; dp < 16; ++dp) {
        const float w = Wm[dp * 16 + c];
        a0 = fmaf(sc[h * 16 + dp],        w, a0);
        a1 = fmaf(sc[64 + h * 16 + dp],   w, a1);
        a2 = fmaf(sc[128 + h * 16 + dp],  w, a2);
      }
      const int base = 960 + sel * 192 + h * 48 + c;   // (h*3+a)*16+c
      sc[base] = a0; sc[base + 16] = a1; sc[base + 32] = a2;
    }
  }
  __syncthreads();

  // ---- P3: M (36 vals, lanes 0-35) + G (wave h computes head h) ----
  if (tid < 36) {
    const int h = tid / 9, ab = tid - h * 9, a = ab / 3, b = ab - a * 3;
    const float* Tp = sc + 960  + h * 48 + a * 16;
    const float* Kp = sc + 1152 + h * 48 + b * 16;
    float s = 0.f;
    #pragma unroll
    for (int c = 0; c < 16; ++c) s = fmaf(Tp[c], Kp[c], s);
    sc[1536 + tid] = s;
  }
  {
    const int e = tid & 63, h = tid >> 6;
    const float* Vp = sc + 1344 + h * 48;
    float q0 = 0.f, q1 = 0.f, q2 = 0.f;
    #pragma unroll
    for (int dp = 0; dp < 16; ++dp) {
      const float wo = Wo[(h * 16 + dp) * 64 + e];
      q0 = fmaf(Vp[dp],      wo, q0);
      q1 = fmaf(Vp[16 + dp], wo, q1);
      q2 = fmaf(Vp[32 + dp], wo, q2);
    }
    sc[1600 + (h * 3 + 0) * 64 + e] = q0;
    sc[1600 + (h * 3 + 1) * 64 + e] = q1;
    sc[1600 + (h * 3 + 2) * 64 + e] = q2;
  }
  __syncthreads();

  // ---- P4: gather per-lane invariants ----
  float m0[9], m1[9];
  #pragma unroll
  for (int i = 0; i < 9; ++i) {
    m0[i] = sc[1536 + (2 * u) * 9 + i];
    m1[i] = sc[1536 + (2 * u + 1) * 9 + i];
  }
  const int hoA = 2 * u, hoB = 2 * u + 1, htA = 2 - 2 * u, htB = 3 - 2 * u;
  float gO0[2], gO1[2], gT0[2], gT1[2];
  #pragma unroll
  for (int a = 0; a < 2; ++a) {
    gO0[a] = sc[1600 + (hoA * 3 + a) * 64 + lane];
    gO1[a] = sc[1600 + (hoB * 3 + a) * 64 + lane];
    gT0[a] = sc[1600 + (htA * 3 + a) * 64 + lane];
    gT1[a] = sc[1600 + (htB * 3 + a) * 64 + lane];
  }
  float c0 = bo[lane];
  #pragma unroll
  for (int h = 0; h < 4; ++h) c0 += sc[1600 + (h * 3 + 2) * 64 + lane];
  const float we0l = sc[lane], we1l = sc[64 + lane], bel = sc[128 + lane];
  const float g1l = g1[lane], b1l_ = bb1[lane];
  const bool masked = (tmask[bidx0 * 32 + n] == 0);
  const bool allm   = (__all((int)masked) != 0);   // wave-uniform; ref: uniform attn
  __syncthreads();   // sc fully consumed; per-wave sh[wv] overlay safe after this

  // ================= Phase A: attention + ao + LN1 (barrier-free) =================
  #pragma unroll 2
  for (int p = 0; p < TPW; ++p) {
    const int m     = tokbase + p;
    const int nstar = (srow0 + p) & 31;

    const float qx = prec[(size_t)m * 64 + nstar * 2];
    const float qy = prec[(size_t)m * 64 + nstar * 2 + 1];
    const float2 pin = *(const float2*)(prec + (size_t)m * 64 + n * 2);

    // en = (cA*x + cB*y + cC)/8, c* = qvec^T M
    const float cA0 = fmaf(qy, m0[3], fmaf(qx, m0[0], m0[6]));
    const float cB0 = fmaf(qy, m0[4], fmaf(qx, m0[1], m0[7]));
    const float cC0 = fmaf(qy, m0[5], fmaf(qx, m0[2], m0[8]));
    const float cA1 = fmaf(qy, m1[3], fmaf(qx, m1[0], m1[6]));
    const float cB1 = fmaf(qy, m1[4], fmaf(qx, m1[1], m1[7]));
    const float cC1 = fmaf(qy, m1[5], fmaf(qx, m1[2], m1[8]));
    const float en0 = fmaf(pin.y, cB0, fmaf(pin.x, cA0, cC0)) * 0.125f;
    const float en1 = fmaf(pin.y, cB1, fmaf(pin.x, cA1, cC1)) * 0.125f;

    float pe0, pe1;
    if (allm) { pe0 = 1.f; pe1 = 1.f; }
    else {
      pe0 = masked ? 0.f : __expf(en0);
      pe1 = masked ? 0.f : __expf(en1);
    }

    // merged butterfly: (pe*x, pe*y, pe) per head
    float r0 = pe0 * pin.x, r1 = pe0 * pin.y, r2 = pe0;
    float r3 = pe1 * pin.x, r4 = pe1 * pin.y, r5 = pe1;
    #pragma unroll
    for (int o = 1; o < 32; o <<= 1) {
      r0 += __shfl_xor(r0, o, 64); r1 += __shfl_xor(r1, o, 64);
      r2 += __shfl_xor(r2, o, 64); r3 += __shfl_xor(r3, o, 64);
      r4 += __shfl_xor(r4, o, 64); r5 += __shfl_xor(r5, o, 64);
    }
    const float o0 = __shfl_xor(r0, 32, 64), o1 = __shfl_xor(r1, 32, 64);
    const float o2 = __shfl_xor(r2, 32, 64), o3 = __shfl_xor(r3, 32, 64);
    const float o4 = __shfl_xor(r4, 32, 64), o5 = __shfl_xor(r5, 32, 64);
    const float i0 = __builtin_amdgcn_rcpf(r2), i1 = __builtin_amdgcn_rcpf(r5);
    const float i2 = __builtin_amdgcn_rcpf(o2), i3 = __builtin_amdgcn_rcpf(o5);

    // v = ao + residual q
    float v = c0;
    v = fmaf(fmaf(r1, gO0[1], r0 * gO0[0]), i0, v);
    v = fmaf(fmaf(r4, gO1[1], r3 * gO1[0]), i1, v);
    v = fmaf(fmaf(o1, gT0[1], o0 * gT0[0]), i2, v);
    v = fmaf(fmaf(o4, gT1[1], o3 * gT1[0]), i3, v);
    v += fmaf(qy, we1l, fmaf(qx, we0l, bel));

    // LN1 (one-pass)
    float sm = v, s2 = v * v;
    #pragma unroll
    for (int o = 1; o < 64; o <<= 1) {
      sm += __shfl_xor(sm, o, 64);
      s2 += __shfl_xor(s2, o, 64);
    }
    const float mu  = sm * (1.f / 64.f);
    const float var = s2 * (1.f / 64.f) - mu * mu;
    const float rs  = rsqrtf(var + 1e-5f);
    sxoh[wv][p][lane] = (v - mu) * rs * g1l + b1l_;
  }
  __syncthreads();   // x visible + align waves so weight streams hit hot L1/L2 lines

  // ================= Phase B: FF + LN2 =================
  // h1 = relu(x @ W1 + b1); lane owns cols 4*lane..4*lane+3 (float4 weight loads)
  float hacc[TPW][4];
  {
    const float4 b1v = *(const float4*)(b1 + 4 * lane);
    #pragma unroll
    for (int t = 0; t < TPW; ++t) {
      hacc[t][0] = b1v.x; hacc[t][1] = b1v.y; hacc[t][2] = b1v.z; hacc[t][3] = b1v.w;
    }
  }
  #pragma unroll 4
  for (int e4 = 0; e4 < 16; ++e4) {
    float4 wr[4];
    #pragma unroll
    for (int kk = 0; kk < 4; ++kk)
      wr[kk] = *(const float4*)(W1 + (e4 * 4 + kk) * 256 + 4 * lane);
    #pragma unroll
    for (int t = 0; t < TPW; ++t) {
      const float4 xv = *(const float4*)&sxoh[wv][t][e4 * 4];
      hacc[t][0] = fmaf(xv.x, wr[0].x, hacc[t][0]);
      hacc[t][1] = fmaf(xv.x, wr[0].y, hacc[t][1]);
      hacc[t][2] = fmaf(xv.x, wr[0].z, hacc[t][2]);
      hacc[t][3] = fmaf(xv.x, wr[0].w, hacc[t][3]);
      hacc[t][0] = fmaf(xv.y, wr[1].x, hacc[t][0]);
      hacc[t][1] = fmaf(xv.y, wr[1].y, hacc[t][1]);
      hacc[t][2] = fmaf(xv.y, wr[1].z, hacc[t][2]);
      hacc[t][3] = fmaf(xv.y, wr[1].w, hacc[t][3]);
      hacc[t][0] = fmaf(xv.z, wr[2].x, hacc[t][0]);
      hacc[t][1] = fmaf(xv.z, wr[2].y, hacc[t][1]);
      hacc[t][2] = fmaf(xv.z, wr[2].z, hacc[t][2]);
      hacc[t][3] = fmaf(xv.z, wr[2].w, hacc[t][3]);
      hacc[t][0] = fmaf(xv.w, wr[3].x, hacc[t][0]);
      hacc[t][1] = fmaf(xv.w, wr[3].y, hacc[t][1]);
      hacc[t][2] = fmaf(xv.w, wr[3].z, hacc[t][2]);
      hacc[t][3] = fmaf(xv.w, wr[3].w, hacc[t][3]);
    }
  }
  float* __restrict__ h1buf = sh[wv];
  #pragma unroll
  for (int t = 0; t < TPW; ++t) {
    float4 hv;
    hv.x = fmaxf(hacc[t][0], 0.f); hv.y = fmaxf(hacc[t][1], 0.f);
    hv.z = fmaxf(hacc[t][2], 0.f); hv.w = fmaxf(hacc[t][3], 0.f);
    *(float4*)&h1buf[t * 256 + 4 * lane] = hv;
  }
  __syncthreads();   // h1 visible + re-align waves for the W2 stream

  // ff2 = h1 @ W2 + b2; lane owns output col `lane`, all 8 tokens
  float f2[TPW];
  {
    const float b2l = b2[lane];
    #pragma unroll
    for (int t = 0; t < TPW; ++t) f2[t] = b2l;
  }
  #pragma unroll 4
  for (int f4 = 0; f4 < 64; ++f4) {
    const float w0 = W2[(f4 * 4 + 0) * 64 + lane];
    const float w1 = W2[(f4 * 4 + 1) * 64 + lane];
    const float w2 = W2[(f4 * 4 + 2) * 64 + lane];
    const float w3 = W2[(f4 * 4 + 3) * 64 + lane];
    #pragma unroll
    for (int t = 0; t < TPW; ++t) {
      const float4 hv = *(const float4*)&h1buf[t * 256 + f4 * 4];
      f2[t] = fmaf(hv.x, w0, f2[t]);
      f2[t] = fmaf(hv.y, w1, f2[t]);
      f2[t] = fmaf(hv.z, w2, f2[t]);
      f2[t] = fmaf(hv.w, w3, f2[t]);
    }
  }

  // LN2 + residual + store
  {
    const float g2l = g2[lane], bb2l = bb2[lane];
    #pragma unroll 2
    for (int t = 0; t < TPW; ++t) {
      const float v = f2[t] + sxoh[wv][t][lane];
      float sm = v, s2 = v * v;
      #pragma unroll
      for (int o = 1; o < 64; o <<= 1) {
        sm += __shfl_xor(sm, o, 64);
        s2 += __shfl_xor(s2, o, 64);
      }
      const float mu  = sm * (1.f / 64.f);
      const float var = s2 * (1.f / 64.f) - mu * mu;
      const float rs  = rsqrtf(var + 1e-5f);
      out[(size_t)(tokbase + t) * 64 + lane] = (v - mu) * rs * g2l + bb2l;
    }
  }
}

} // namespace

extern "C" void kernel_launch(void* const* d_in, const int* in_sizes, int n_in,
                              void* d_out, int out_size, void* d_ws, size_t ws_size,
                              hipStream_t stream) {
  (void)in_sizes; (void)n_in; (void)d_ws; (void)ws_size; (void)out_size;
  const float* prec = (const float*)d_in[0];
  const int*   tm   = (const int*)  d_in[1];
  const float* We   = (const float*)d_in[2];
  const float* be   = (const float*)d_in[3];
  const float* Wq   = (const float*)d_in[4];
  const float* Wk   = (const float*)d_in[5];
  const float* Wv   = (const float*)d_in[6];
  const float* Wo   = (const float*)d_in[7];
  const float* bo   = (const float*)d_in[8];
  const float* g1   = (const float*)d_in[9];
  const float* bb1  = (const float*)d_in[10];
  const float* W1   = (const float*)d_in[11];
  const float* b1   = (const float*)d_in[12];
  const float* W2   = (const float*)d_in[13];
  const float* b2   = (const float*)d_in[14];
  const float* g2   = (const float*)d_in[15];
  const float* bb2  = (const float*)d_in[16];

  dim3 grid(768), block(256);
  hipLaunchKernelGGL(prec_fused, grid, block, 0, stream,
                     prec, tm, We, be, Wq, Wk, Wv, Wo, bo, g1, bb1,
                     W1, b1, W2, b2, g2, bb2, (float*)d_out);
}

// Round 7
// 133.678 us; speedup vs baseline: 1.1595x; 1.0471x over previous
//
#include <hip/hip_runtime.h>
#include <math.h>

// Shapes: B=128, S=192, N=32, PREC_DIM=2, E=64, H=4, D=16, FF=256, M=24576.
//
// Algebra: pv_n = Ue^T pvec_n, pvec=(x,y,1), Ue=[We0;We1;be] (3x64).
// energy[h][n] = qvec^T M_h pvec_n,  M_h = Te_h Ke_h^T (3x3),
//   Te_h = Ue_h Wq, Ke_h = Ue_h Wk (3x16 each).
// ao[e] = sum_h ctx_h . G_h[:,e] + bo,  G_h = (Ue_h Wv) Wo_h (3x64),
//   ctx_h = (sum_n w x, sum_n w y, 1),  w = softmax weights.
//
// Work split: a PAIR of waves owns 8 tokens. Each wave: phase A for 4 tokens;
// phase B computes half of W1-cols (all 8 tokens) and half of W2-rows
// (partial f2, exchanged via LDS). Per-wave weight traffic halves vs TPW=8
// single-wave; waves double to 24/CU.
namespace {

constexpr int S_  = 192;
constexpr int TPP = 8;   // tokens per pair
constexpr int PPB = 2;   // pairs per block (4 waves, 256 threads)
// grid = 24576 / 16 = 1536 blocks = 6 blocks/CU = 24 waves/CU

__device__ __forceinline__ void wave_fence() {
  asm volatile("s_waitcnt lgkmcnt(0)" ::: "memory");
}

__launch_bounds__(256)
__attribute__((amdgpu_waves_per_eu(6, 8)))   // grid gives 6 waves/EU; cap VGPR ~85
__global__ void prec_fused(
    const float* __restrict__ prec,  const int*   __restrict__ tmask,
    const float* __restrict__ We,    const float* __restrict__ be,
    const float* __restrict__ Wq,    const float* __restrict__ Wk,
    const float* __restrict__ Wv,    const float* __restrict__ Wo,
    const float* __restrict__ bo,    const float* __restrict__ g1,
    const float* __restrict__ bb1,   const float* __restrict__ W1,
    const float* __restrict__ b1,    const float* __restrict__ W2,
    const float* __restrict__ b2,    const float* __restrict__ g2,
    const float* __restrict__ bb2,   float* __restrict__ out)
{
  // sh: prologue scratch (flat 4096 floats), then per-pair h1[8][256], then fpart overlay
  __shared__ __align__(16) float sh[PPB][2048];
  __shared__ __align__(16) float sxoh[PPB][TPP][64];   // LN1 output x

  const int tid   = threadIdx.x;
  const int wv    = tid >> 6;
  const int pairL = wv >> 1;    // pair within block
  const int w2    = wv & 1;     // wave within pair
  const int lane  = tid & 63;
  const int u     = lane >> 5;  // half index (heads 2u,2u+1)
  const int n     = lane & 31;  // precedence slot
  const int pairbase = (blockIdx.x * PPB + pairL) * TPP;
  const int bidx0 = pairbase / S_;            // batch constant per pair (192%16==0)
  const int srow0 = pairbase - bidx0 * S_;

  float* __restrict__ sc = &sh[0][0];
  // sc layout (floats): 0:Ue0[64] 64:Ue1[64] 128:be[64] 192:Wq[256] 448:Wk[256]
  //  704:Wv[256] 960:Te[192] 1152:Ke[192] 1344:Ve[192] 1536:M[36] 1600:G[768]

  // ---- P1: stage small weights (block-cooperative) ----
  if (tid < 64) { sc[tid] = We[tid]; sc[64 + tid] = We[64 + tid]; sc[128 + tid] = be[tid]; }
  sc[192 + tid] = Wq[tid];
  sc[448 + tid] = Wk[tid];
  sc[704 + tid] = Wv[tid];
  __syncthreads();

  // ---- P2: Te/Ke/Ve = Ue_h @ {Wq,Wk,Wv} (one wave per matrix; wave 3 idle) ----
  {
    const int sel = wv;
    if (sel < 3) {
      const int h = (tid >> 4) & 3, c = tid & 15;
      const float* Wm = sc + 192 + sel * 256;
      float a0 = 0.f, a1 = 0.f, a2 = 0.f;
      #pragma unroll
      for (int dp = 0; dp < 16; ++dp) {
        const float w = Wm[dp * 16 + c];
        a0 = fmaf(sc[h * 16 + dp],       w, a0);
        a1 = fmaf(sc[64 + h * 16 + dp],  w, a1);
        a2 = fmaf(sc[128 + h * 16 + dp], w, a2);
      }
      const int base = 960 + sel * 192 + h * 48 + c;
      sc[base] = a0; sc[base + 16] = a1; sc[base + 32] = a2;
    }
  }
  __syncthreads();

  // ---- P3: M (36 vals) + G (wave h computes head h) ----
  if (tid < 36) {
    const int h = tid / 9, ab = tid - h * 9, a = ab / 3, b = ab - a * 3;
    const float* Tp = sc + 960  + h * 48 + a * 16;
    const float* Kp = sc + 1152 + h * 48 + b * 16;
    float s = 0.f;
    #pragma unroll
    for (int c = 0; c < 16; ++c) s = fmaf(Tp[c], Kp[c], s);
    sc[1536 + tid] = s;
  }
  {
    const int e = tid & 63, h = wv;
    const float* Vp = sc + 1344 + h * 48;
    float q0 = 0.f, q1 = 0.f, q2 = 0.f;
    #pragma unroll
    for (int dp = 0; dp < 16; ++dp) {
      const float wo = Wo[(h * 16 + dp) * 64 + e];
      q0 = fmaf(Vp[dp],      wo, q0);
      q1 = fmaf(Vp[16 + dp], wo, q1);
      q2 = fmaf(Vp[32 + dp], wo, q2);
    }
    sc[1600 + (h * 3 + 0) * 64 + e] = q0;
    sc[1600 + (h * 3 + 1) * 64 + e] = q1;
    sc[1600 + (h * 3 + 2) * 64 + e] = q2;
  }
  __syncthreads();

  // ---- P4: gather per-lane invariants ----
  float m0[9], m1[9];
  #pragma unroll
  for (int i = 0; i < 9; ++i) {
    m0[i] = sc[1536 + (2 * u) * 9 + i];
    m1[i] = sc[1536 + (2 * u + 1) * 9 + i];
  }
  const int hoA = 2 * u, hoB = 2 * u + 1, htA = 2 - 2 * u, htB = 3 - 2 * u;
  float gO0[2], gO1[2], gT0[2], gT1[2];
  #pragma unroll
  for (int a = 0; a < 2; ++a) {
    gO0[a] = sc[1600 + (hoA * 3 + a) * 64 + lane];
    gO1[a] = sc[1600 + (hoB * 3 + a) * 64 + lane];
    gT0[a] = sc[1600 + (htA * 3 + a) * 64 + lane];
    gT1[a] = sc[1600 + (htB * 3 + a) * 64 + lane];
  }
  float c0 = bo[lane];
  #pragma unroll
  for (int h = 0; h < 4; ++h) c0 += sc[1600 + (h * 3 + 2) * 64 + lane];
  const float we0l = sc[lane], we1l = sc[64 + lane], bel = sc[128 + lane];
  const float g1l = g1[lane], b1l_ = bb1[lane];
  const bool masked = (tmask[bidx0 * 32 + n] == 0);
  const bool allm   = (__all((int)masked) != 0);
  __syncthreads();   // sc fully consumed

  // ========== Phase A: attention + ao + LN1, 4 tokens per wave ==========
  #pragma unroll 2
  for (int p = 0; p < 4; ++p) {
    const int tl    = w2 * 4 + p;             // token index within pair
    const int m     = pairbase + tl;
    const int nstar = (srow0 + tl) & 31;

    const float qx = prec[(size_t)m * 64 + nstar * 2];
    const float qy = prec[(size_t)m * 64 + nstar * 2 + 1];
    const float2 pin = *(const float2*)(prec + (size_t)m * 64 + n * 2);

    const float cA0 = fmaf(qy, m0[3], fmaf(qx, m0[0], m0[6]));
    const float cB0 = fmaf(qy, m0[4], fmaf(qx, m0[1], m0[7]));
    const float cC0 = fmaf(qy, m0[5], fmaf(qx, m0[2], m0[8]));
    const float cA1 = fmaf(qy, m1[3], fmaf(qx, m1[0], m1[6]));
    const float cB1 = fmaf(qy, m1[4], fmaf(qx, m1[1], m1[7]));
    const float cC1 = fmaf(qy, m1[5], fmaf(qx, m1[2], m1[8]));
    const float en0 = fmaf(pin.y, cB0, fmaf(pin.x, cA0, cC0)) * 0.125f;
    const float en1 = fmaf(pin.y, cB1, fmaf(pin.x, cA1, cC1)) * 0.125f;

    float pe0, pe1;
    if (allm) { pe0 = 1.f; pe1 = 1.f; }
    else {
      pe0 = masked ? 0.f : __expf(en0);
      pe1 = masked ? 0.f : __expf(en1);
    }

    float r0 = pe0 * pin.x, r1 = pe0 * pin.y, r2 = pe0;
    float r3 = pe1 * pin.x, r4 = pe1 * pin.y, r5 = pe1;
    #pragma unroll
    for (int o = 1; o < 32; o <<= 1) {
      r0 += __shfl_xor(r0, o, 64); r1 += __shfl_xor(r1, o, 64);
      r2 += __shfl_xor(r2, o, 64); r3 += __shfl_xor(r3, o, 64);
      r4 += __shfl_xor(r4, o, 64); r5 += __shfl_xor(r5, o, 64);
    }
    const float o0 = __shfl_xor(r0, 32, 64), o1 = __shfl_xor(r1, 32, 64);
    const float o2 = __shfl_xor(r2, 32, 64), o3 = __shfl_xor(r3, 32, 64);
    const float o4 = __shfl_xor(r4, 32, 64), o5 = __shfl_xor(r5, 32, 64);
    const float i0 = __builtin_amdgcn_rcpf(r2), i1 = __builtin_amdgcn_rcpf(r5);
    const float i2 = __builtin_amdgcn_rcpf(o2), i3 = __builtin_amdgcn_rcpf(o5);

    float v = c0;
    v = fmaf(fmaf(r1, gO0[1], r0 * gO0[0]), i0, v);
    v = fmaf(fmaf(r4, gO1[1], r3 * gO1[0]), i1, v);
    v = fmaf(fmaf(o1, gT0[1], o0 * gT0[0]), i2, v);
    v = fmaf(fmaf(o4, gT1[1], o3 * gT1[0]), i3, v);
    v += fmaf(qy, we1l, fmaf(qx, we0l, bel));

    float sm = v, s2 = v * v;
    #pragma unroll
    for (int o = 1; o < 64; o <<= 1) {
      sm += __shfl_xor(sm, o, 64);
      s2 += __shfl_xor(s2, o, 64);
    }
    const float mu  = sm * (1.f / 64.f);
    const float var = s2 * (1.f / 64.f) - mu * mu;
    const float rs  = rsqrtf(var + 1e-5f);
    sxoh[pairL][tl][lane] = (v - mu) * rs * g1l + b1l_;
  }
  __syncthreads();   // all 8 tokens' x visible to the pair

  // ========== Phase B: FF split across the pair ==========
  // h1 half: wave w2 computes cols c2 = 128*w2 + 2*lane (+1), all 8 tokens
  const int c2 = 128 * w2 + 2 * lane;
  float hacc[TPP][2];
  {
    const float2 b1v = *(const float2*)(b1 + c2);
    #pragma unroll
    for (int t = 0; t < TPP; ++t) { hacc[t][0] = b1v.x; hacc[t][1] = b1v.y; }
  }
  #pragma unroll 4
  for (int e4 = 0; e4 < 16; ++e4) {
    float2 wr[4];
    #pragma unroll
    for (int kk = 0; kk < 4; ++kk)
      wr[kk] = *(const float2*)(W1 + (e4 * 4 + kk) * 256 + c2);
    #pragma unroll
    for (int t = 0; t < TPP; ++t) {
      const float4 xv = *(const float4*)&sxoh[pairL][t][e4 * 4];
      hacc[t][0] = fmaf(xv.x, wr[0].x, hacc[t][0]);
      hacc[t][1] = fmaf(xv.x, wr[0].y, hacc[t][1]);
      hacc[t][0] = fmaf(xv.y, wr[1].x, hacc[t][0]);
      hacc[t][1] = fmaf(xv.y, wr[1].y, hacc[t][1]);
      hacc[t][0] = fmaf(xv.z, wr[2].x, hacc[t][0]);
      hacc[t][1] = fmaf(xv.z, wr[2].y, hacc[t][1]);
      hacc[t][0] = fmaf(xv.w, wr[3].x, hacc[t][0]);
      hacc[t][1] = fmaf(xv.w, wr[3].y, hacc[t][1]);
    }
  }
  float* __restrict__ h1buf = sh[pairL];
  #pragma unroll
  for (int t = 0; t < TPP; ++t) {
    float2 hv;
    hv.x = fmaxf(hacc[t][0], 0.f);
    hv.y = fmaxf(hacc[t][1], 0.f);
    *(float2*)&h1buf[t * 256 + c2] = hv;
  }
  wave_fence();   // own-half h1 written by this wave, read back by this wave only

  // ff2 partial: wave w2 sums f in [128*w2, 128*w2+128) for all 8 tokens
  float f2[TPP];
  #pragma unroll
  for (int t = 0; t < TPP; ++t) f2[t] = 0.f;
  #pragma unroll 4
  for (int k = 0; k < 32; ++k) {
    const int f4 = 32 * w2 + k;
    const float w0 = W2[(f4 * 4 + 0) * 64 + lane];
    const float w1 = W2[(f4 * 4 + 1) * 64 + lane];
    const float w2_ = W2[(f4 * 4 + 2) * 64 + lane];
    const float w3 = W2[(f4 * 4 + 3) * 64 + lane];
    #pragma unroll
    for (int t = 0; t < TPP; ++t) {
      const float4 hv = *(const float4*)&h1buf[t * 256 + f4 * 4];
      f2[t] = fmaf(hv.x, w0, f2[t]);
      f2[t] = fmaf(hv.y, w1, f2[t]);
      f2[t] = fmaf(hv.z, w2_, f2[t]);
      f2[t] = fmaf(hv.w, w3, f2[t]);
    }
  }
  __syncthreads();   // all h1 reads done; h1buf may be overlaid

  // exchange partials: wave w2 writes partials for the 4 tokens it does NOT finalize
  float* __restrict__ fpart = h1buf;   // overlay [8][64]
  {
    const int tb = (1 - w2) * 4;
    #pragma unroll
    for (int i = 0; i < 4; ++i)
      fpart[(tb + i) * 64 + lane] = f2[tb + i];
  }
  __syncthreads();

  // LN2 + residual + store: wave finalizes its own 4 tokens
  {
    const float b2l = b2[lane], g2l = g2[lane], bb2l = bb2[lane];
    #pragma unroll 2
    for (int i = 0; i < 4; ++i) {
      const int tl = w2 * 4 + i;
      const float v = f2[tl] + fpart[tl * 64 + lane] + b2l + sxoh[pairL][tl][lane];
      float sm = v, s2 = v * v;
      #pragma unroll
      for (int o = 1; o < 64; o <<= 1) {
        sm += __shfl_xor(sm, o, 64);
        s2 += __shfl_xor(s2, o, 64);
      }
      const float mu  = sm * (1.f / 64.f);
      const float var = s2 * (1.f / 64.f) - mu * mu;
      const float rs  = rsqrtf(var + 1e-5f);
      out[(size_t)(pairbase + tl) * 64 + lane] = (v - mu) * rs * g2l + bb2l;
    }
  }
}

} // namespace

extern "C" void kernel_launch(void* const* d_in, const int* in_sizes, int n_in,
                              void* d_out, int out_size, void* d_ws, size_t ws_size,
                              hipStream_t stream) {
  (void)in_sizes; (void)n_in; (void)d_ws; (void)ws_size; (void)out_size;
  const float* prec = (const float*)d_in[0];
  const int*   tm   = (const int*)  d_in[1];
  const float* We   = (const float*)d_in[2];
  const float* be   = (const float*)d_in[3];
  const float* Wq   = (const float*)d_in[4];
  const float* Wk   = (const float*)d_in[5];
  const float* Wv   = (const float*)d_in[6];
  const float* Wo   = (const float*)d_in[7];
  const float* bo   = (const float*)d_in[8];
  const float* g1   = (const float*)d_in[9];
  const float* bb1  = (const float*)d_in[10];
  const float* W1   = (const float*)d_in[11];
  const float* b1   = (const float*)d_in[12];
  const float* W2   = (const float*)d_in[13];
  const float* b2   = (const float*)d_in[14];
  const float* g2   = (const float*)d_in[15];
  const float* bb2  = (const float*)d_in[16];

  dim3 grid(1536), block(256);
  hipLaunchKernelGGL(prec_fused, grid, block, 0, stream,
                     prec, tm, We, be, Wq, Wk, Wv, Wo, bo, g1, bb1,
                     W1, b1, W2, b2, g2, bb2, (float*)d_out);
}

// Round 11
// 130.780 us; speedup vs baseline: 1.1852x; 1.0222x over previous
//
#include <hip/hip_runtime.h>
#include <math.h>

// Shapes: B=128, S=192, N=32, PREC_DIM=2, E=64, H=4, D=16, FF=256, M=24576.
//
// Algebra: pv_n = Ue^T pvec_n, pvec=(x,y,1), Ue=[We0;We1;be] (3x64).
// energy[h][n] = qvec^T M_h pvec_n,  M_h = Te_h Ke_h^T (3x3),
//   Te_h = Ue_h Wq, Ke_h = Ue_h Wk (3x16 each).
// ao[e] = sum_h ctx_h . G_h[:,e] + bo,  G_h = (Ue_h Wv) Wo_h (3x64),
//   ctx_h = (sum_n w x, sum_n w y, 1),  w = softmax weights.
//
// Pair of waves owns 8 tokens; wave w2 streams f-half of W1/W2 (keeps R6's
// weight reuse). NEW: broadcast LDS reads are lane-half split (2-addr uniform
// reads are free), halving DS ops in W1/ff2 stages; xor1/xor2 butterfly steps
// run as DPP adds on the VALU instead of ds_swizzle.
namespace {

constexpr int S_  = 192;
constexpr int TPP = 8;   // tokens per pair
constexpr int PPB = 2;   // pairs per block (4 waves); grid = 1536

__device__ __forceinline__ void wave_fence() {
  asm volatile("s_waitcnt lgkmcnt(0)" ::: "memory");
}
// x + xor1(x) / x + xor2(x) via DPP quad_perm (VALU, off the LDS pipe)
__device__ __forceinline__ float dpp_xor1_add(float x) {
  return x + __int_as_float(__builtin_amdgcn_update_dpp(
      0, __float_as_int(x), 0xB1, 0xF, 0xF, true));
}
__device__ __forceinline__ float dpp_xor2_add(float x) {
  return x + __int_as_float(__builtin_amdgcn_update_dpp(
      0, __float_as_int(x), 0x4E, 0xF, 0xF, true));
}

__launch_bounds__(256)
__attribute__((amdgpu_waves_per_eu(6, 8)))
__global__ void prec_fused(
    const float* __restrict__ prec,  const int*   __restrict__ tmask,
    const float* __restrict__ We,    const float* __restrict__ be,
    const float* __restrict__ Wq,    const float* __restrict__ Wk,
    const float* __restrict__ Wv,    const float* __restrict__ Wo,
    const float* __restrict__ bo,    const float* __restrict__ g1,
    const float* __restrict__ bb1,   const float* __restrict__ W1,
    const float* __restrict__ b1,    const float* __restrict__ W2,
    const float* __restrict__ b2,    const float* __restrict__ g2,
    const float* __restrict__ bb2,   float* __restrict__ out)
{
  __shared__ __align__(16) float sh[PPB][2048];        // prologue sc / h1[8][256]
  __shared__ __align__(16) float sxoh[PPB][TPP][64];   // LN1 output x
  __shared__ __align__(16) float sfp[PPB][TPP][64];    // ff2 partial exchange

  const int tid   = threadIdx.x;
  const int wv    = tid >> 6;
  const int pairL = wv >> 1;
  const int w2    = wv & 1;
  const int lane  = tid & 63;
  const int u     = lane >> 5;
  const int n     = lane & 31;
  const int pairbase = (blockIdx.x * PPB + pairL) * TPP;
  const int bidx0 = pairbase / S_;
  const int srow0 = pairbase - bidx0 * S_;

  float* __restrict__ sc = &sh[0][0];
  // sc layout: 0:Ue0[64] 64:Ue1[64] 128:be[64] 192:Wq[256] 448:Wk[256]
  //  704:Wv[256] 960:Te[192] 1152:Ke[192] 1344:Ve[192] 1536:M[36] 1600:G[768]

  // ---- P1: stage small weights ----
  if (tid < 64) { sc[tid] = We[tid]; sc[64 + tid] = We[64 + tid]; sc[128 + tid] = be[tid]; }
  sc[192 + tid] = Wq[tid];
  sc[448 + tid] = Wk[tid];
  sc[704 + tid] = Wv[tid];
  __syncthreads();

  // ---- P2: Te/Ke/Ve = Ue_h @ {Wq,Wk,Wv} ----
  if (wv < 3) {
    const int h = (tid >> 4) & 3, cc = tid & 15;
    const float* Wm = sc + 192 + wv * 256;
    float a0 = 0.f, a1 = 0.f, a2 = 0.f;
    #pragma unroll
    for (int dp = 0; dp < 16; ++dp) {
      const float w = Wm[dp * 16 + cc];
      a0 = fmaf(sc[h * 16 + dp],       w, a0);
      a1 = fmaf(sc[64 + h * 16 + dp],  w, a1);
      a2 = fmaf(sc[128 + h * 16 + dp], w, a2);
    }
    const int base = 960 + wv * 192 + h * 48 + cc;
    sc[base] = a0; sc[base + 16] = a1; sc[base + 32] = a2;
  }
  __syncthreads();

  // ---- P3: M + G ----
  if (tid < 36) {
    const int h = tid / 9, ab = tid - h * 9, a = ab / 3, b = ab - a * 3;
    const float* Tp = sc + 960  + h * 48 + a * 16;
    const float* Kp = sc + 1152 + h * 48 + b * 16;
    float s = 0.f;
    #pragma unroll
    for (int cc = 0; cc < 16; ++cc) s = fmaf(Tp[cc], Kp[cc], s);
    sc[1536 + tid] = s;
  }
  {
    const int e = tid & 63, h = wv;
    const float* Vp = sc + 1344 + h * 48;
    float q0 = 0.f, q1 = 0.f, q2 = 0.f;
    #pragma unroll
    for (int dp = 0; dp < 16; ++dp) {
      const float wo = Wo[(h * 16 + dp) * 64 + e];
      q0 = fmaf(Vp[dp],      wo, q0);
      q1 = fmaf(Vp[16 + dp], wo, q1);
      q2 = fmaf(Vp[32 + dp], wo, q2);
    }
    sc[1600 + (h * 3 + 0) * 64 + e] = q0;
    sc[1600 + (h * 3 + 1) * 64 + e] = q1;
    sc[1600 + (h * 3 + 2) * 64 + e] = q2;
  }
  __syncthreads();

  // ---- P4: gather per-lane invariants ----
  float m0[9], m1[9];
  #pragma unroll
  for (int i = 0; i < 9; ++i) {
    m0[i] = sc[1536 + (2 * u) * 9 + i];
    m1[i] = sc[1536 + (2 * u + 1) * 9 + i];
  }
  const int hoA = 2 * u, hoB = 2 * u + 1, htA = 2 - 2 * u, htB = 3 - 2 * u;
  float gO0[2], gO1[2], gT0[2], gT1[2];
  #pragma unroll
  for (int a = 0; a < 2; ++a) {
    gO0[a] = sc[1600 + (hoA * 3 + a) * 64 + lane];
    gO1[a] = sc[1600 + (hoB * 3 + a) * 64 + lane];
    gT0[a] = sc[1600 + (htA * 3 + a) * 64 + lane];
    gT1[a] = sc[1600 + (htB * 3 + a) * 64 + lane];
  }
  float c0 = bo[lane];
  #pragma unroll
  for (int h = 0; h < 4; ++h) c0 += sc[1600 + (h * 3 + 2) * 64 + lane];
  const float we0l = sc[lane], we1l = sc[64 + lane], bel = sc[128 + lane];
  const float g1l = g1[lane], b1l_ = bb1[lane];
  const bool masked = (tmask[bidx0 * 32 + n] == 0);
  const bool allm   = (__all((int)masked) != 0);
  __syncthreads();   // sc fully consumed

  // ========== Phase A: attention + ao + LN1, 4 tokens per wave ==========
  #pragma unroll 2
  for (int p = 0; p < 4; ++p) {
    const int tl    = w2 * 4 + p;
    const int m     = pairbase + tl;
    const int nstar = (srow0 + tl) & 31;

    const float qx = prec[(size_t)m * 64 + nstar * 2];
    const float qy = prec[(size_t)m * 64 + nstar * 2 + 1];
    const float2 pin = *(const float2*)(prec + (size_t)m * 64 + n * 2);

    const float cA0 = fmaf(qy, m0[3], fmaf(qx, m0[0], m0[6]));
    const float cB0 = fmaf(qy, m0[4], fmaf(qx, m0[1], m0[7]));
    const float cC0 = fmaf(qy, m0[5], fmaf(qx, m0[2], m0[8]));
    const float cA1 = fmaf(qy, m1[3], fmaf(qx, m1[0], m1[6]));
    const float cB1 = fmaf(qy, m1[4], fmaf(qx, m1[1], m1[7]));
    const float cC1 = fmaf(qy, m1[5], fmaf(qx, m1[2], m1[8]));
    const float en0 = fmaf(pin.y, cB0, fmaf(pin.x, cA0, cC0)) * 0.125f;
    const float en1 = fmaf(pin.y, cB1, fmaf(pin.x, cA1, cC1)) * 0.125f;

    float pe0, pe1;
    if (allm) { pe0 = 1.f; pe1 = 1.f; }
    else {
      pe0 = masked ? 0.f : __expf(en0);
      pe1 = masked ? 0.f : __expf(en1);
    }

    // merged butterfly (xor1,2 on DPP; 4,8,16 via shfl)
    float r0 = pe0 * pin.x, r1 = pe0 * pin.y, r2 = pe0;
    float r3 = pe1 * pin.x, r4 = pe1 * pin.y, r5 = pe1;
    r0 = dpp_xor1_add(r0); r1 = dpp_xor1_add(r1); r2 = dpp_xor1_add(r2);
    r3 = dpp_xor1_add(r3); r4 = dpp_xor1_add(r4); r5 = dpp_xor1_add(r5);
    r0 = dpp_xor2_add(r0); r1 = dpp_xor2_add(r1); r2 = dpp_xor2_add(r2);
    r3 = dpp_xor2_add(r3); r4 = dpp_xor2_add(r4); r5 = dpp_xor2_add(r5);
    #pragma unroll
    for (int o = 4; o < 32; o <<= 1) {
      r0 += __shfl_xor(r0, o, 64); r1 += __shfl_xor(r1, o, 64);
      r2 += __shfl_xor(r2, o, 64); r3 += __shfl_xor(r3, o, 64);
      r4 += __shfl_xor(r4, o, 64); r5 += __shfl_xor(r5, o, 64);
    }
    const float o0 = __shfl_xor(r0, 32, 64), o1 = __shfl_xor(r1, 32, 64);
    const float o2 = __shfl_xor(r2, 32, 64), o3 = __shfl_xor(r3, 32, 64);
    const float o4 = __shfl_xor(r4, 32, 64), o5 = __shfl_xor(r5, 32, 64);
    const float i0 = __builtin_amdgcn_rcpf(r2), i1 = __builtin_amdgcn_rcpf(r5);
    const float i2 = __builtin_amdgcn_rcpf(o2), i3 = __builtin_amdgcn_rcpf(o5);

    float v = c0;
    v = fmaf(fmaf(r1, gO0[1], r0 * gO0[0]), i0, v);
    v = fmaf(fmaf(r4, gO1[1], r3 * gO1[0]), i1, v);
    v = fmaf(fmaf(o1, gT0[1], o0 * gT0[0]), i2, v);
    v = fmaf(fmaf(o4, gT1[1], o3 * gT1[0]), i3, v);
    v += fmaf(qy, we1l, fmaf(qx, we0l, bel));

    // LN1: xor1,2 DPP; 4..32 shfl
    float sm = v, s2 = v * v;
    sm = dpp_xor1_add(sm); s2 = dpp_xor1_add(s2);
    sm = dpp_xor2_add(sm); s2 = dpp_xor2_add(s2);
    #pragma unroll
    for (int o = 4; o < 64; o <<= 1) {
      sm += __shfl_xor(sm, o, 64);
      s2 += __shfl_xor(s2, o, 64);
    }
    const float mu  = sm * (1.f / 64.f);
    const float var = s2 * (1.f / 64.f) - mu * mu;
    const float rs  = rsqrtf(var + 1e-5f);
    sxoh[pairL][tl][lane] = (v - mu) * rs * g1l + b1l_;
  }
  __syncthreads();   // x for all 8 tokens visible across the pair

  // ========== Phase B: FF (f-half per wave, lane-half split broadcasts) ==========
  const int q  = lane >> 5;    // lane half
  const int l5 = lane & 31;
  const int F0 = 128 * w2;     // this wave's W1-col / W2-row half

  // W1 stage: cols c..c+3 (c = F0+4*l5), tokens 4q..4q+3 per lane-half
  const int c = F0 + 4 * l5;
  float hacc[4][4];
  {
    const float4 b1v = *(const float4*)(b1 + c);
    #pragma unroll
    for (int p = 0; p < 4; ++p) {
      hacc[p][0] = b1v.x; hacc[p][1] = b1v.y; hacc[p][2] = b1v.z; hacc[p][3] = b1v.w;
    }
  }
  #pragma unroll 4
  for (int e4 = 0; e4 < 16; ++e4) {
    float4 w1r[4];
    #pragma unroll
    for (int j = 0; j < 4; ++j)
      w1r[j] = *(const float4*)(W1 + (e4 * 4 + j) * 256 + c);
    #pragma unroll
    for (int p = 0; p < 4; ++p) {
      const float4 xv = *(const float4*)&sxoh[pairL][4 * q + p][e4 * 4];
      hacc[p][0] = fmaf(xv.x, w1r[0].x, hacc[p][0]);
      hacc[p][1] = fmaf(xv.x, w1r[0].y, hacc[p][1]);
      hacc[p][2] = fmaf(xv.x, w1r[0].z, hacc[p][2]);
      hacc[p][3] = fmaf(xv.x, w1r[0].w, hacc[p][3]);
      hacc[p][0] = fmaf(xv.y, w1r[1].x, hacc[p][0]);
      hacc[p][1] = fmaf(xv.y, w1r[1].y, hacc[p][1]);
      hacc[p][2] = fmaf(xv.y, w1r[1].z, hacc[p][2]);
      hacc[p][3] = fmaf(xv.y, w1r[1].w, hacc[p][3]);
      hacc[p][0] = fmaf(xv.z, w1r[2].x, hacc[p][0]);
      hacc[p][1] = fmaf(xv.z, w1r[2].y, hacc[p][1]);
      hacc[p][2] = fmaf(xv.z, w1r[2].z, hacc[p][2]);
      hacc[p][3] = fmaf(xv.z, w1r[2].w, hacc[p][3]);
      hacc[p][0] = fmaf(xv.w, w1r[3].x, hacc[p][0]);
      hacc[p][1] = fmaf(xv.w, w1r[3].y, hacc[p][1]);
      hacc[p][2] = fmaf(xv.w, w1r[3].z, hacc[p][2]);
      hacc[p][3] = fmaf(xv.w, w1r[3].w, hacc[p][3]);
    }
  }
  float* __restrict__ h1buf = sh[pairL];
  #pragma unroll
  for (int p = 0; p < 4; ++p) {
    float4 hv;
    hv.x = fmaxf(hacc[p][0], 0.f); hv.y = fmaxf(hacc[p][1], 0.f);
    hv.z = fmaxf(hacc[p][2], 0.f); hv.w = fmaxf(hacc[p][3], 0.f);
    *(float4*)&h1buf[(4 * q + p) * 256 + c] = hv;
  }
  wave_fence();   // own-wave h1 (both lane-halves) visible to own wave

  // ff2: lane-half q covers f-quarter [F0+64q, F0+64q+64), cols e0,e0+1
  const int e0 = 2 * l5;
  const int f4base = 32 * w2 + 16 * q;
  float2 f2a[8];
  #pragma unroll
  for (int t = 0; t < 8; ++t) { f2a[t].x = 0.f; f2a[t].y = 0.f; }
  #pragma unroll 4
  for (int k = 0; k < 16; ++k) {
    const int f4 = f4base + k;
    float2 w2r[4];
    #pragma unroll
    for (int j = 0; j < 4; ++j)
      w2r[j] = *(const float2*)(W2 + (f4 * 4 + j) * 64 + e0);
    #pragma unroll
    for (int t = 0; t < 8; ++t) {
      const float4 hv = *(const float4*)&h1buf[t * 256 + f4 * 4];
      f2a[t].x = fmaf(hv.x, w2r[0].x, f2a[t].x);
      f2a[t].y = fmaf(hv.x, w2r[0].y, f2a[t].y);
      f2a[t].x = fmaf(hv.y, w2r[1].x, f2a[t].x);
      f2a[t].y = fmaf(hv.y, w2r[1].y, f2a[t].y);
      f2a[t].x = fmaf(hv.z, w2r[2].x, f2a[t].x);
      f2a[t].y = fmaf(hv.z, w2r[2].y, f2a[t].y);
      f2a[t].x = fmaf(hv.w, w2r[3].x, f2a[t].x);
      f2a[t].y = fmaf(hv.w, w2r[3].y, f2a[t].y);
    }
  }
  // combine the two f-quarters (lane halves)
  #pragma unroll
  for (int t = 0; t < 8; ++t) {
    f2a[t].x += __shfl_xor(f2a[t].x, 32, 64);
    f2a[t].y += __shfl_xor(f2a[t].y, 32, 64);
  }
  // cross-wave partial exchange (write the other wave's tokens)
  if (lane < 32) {
    if (w2 == 0) {
      #pragma unroll
      for (int i = 0; i < 4; ++i) *(float2*)&sfp[pairL][4 + i][e0] = f2a[4 + i];
    } else {
      #pragma unroll
      for (int i = 0; i < 4; ++i) *(float2*)&sfp[pairL][i][e0] = f2a[i];
    }
  }
  __syncthreads();

  // finalize: lane-half q handles tokens w2*4 + 2q + {0,1}; LN2 over 32 lanes x 2 cols
  {
    const float2 b2v  = *(const float2*)(b2 + e0);
    const float2 g2v  = *(const float2*)(g2 + e0);
    const float2 bb2v = *(const float2*)(bb2 + e0);
    #pragma unroll
    for (int i = 0; i < 2; ++i) {
      float2 mine;
      if (w2 == 0) mine = q ? f2a[2 + i] : f2a[i];
      else         mine = q ? f2a[6 + i] : f2a[4 + i];
      const int tl = w2 * 4 + 2 * q + i;
      const float2 fp = *(const float2*)&sfp[pairL][tl][e0];
      const float2 xr = *(const float2*)&sxoh[pairL][tl][e0];
      const float v0 = mine.x + fp.x + b2v.x + xr.x;
      const float v1 = mine.y + fp.y + b2v.y + xr.y;
      float sm = v0 + v1, s2v = v0 * v0 + v1 * v1;
      sm = dpp_xor1_add(sm); s2v = dpp_xor1_add(s2v);
      sm = dpp_xor2_add(sm); s2v = dpp_xor2_add(s2v);
      #pragma unroll
      for (int o = 4; o < 32; o <<= 1) {
        sm  += __shfl_xor(sm, o, 64);
        s2v += __shfl_xor(s2v, o, 64);
      }
      const float mu  = sm * (1.f / 64.f);
      const float var = s2v * (1.f / 64.f) - mu * mu;
      const float rs  = rsqrtf(var + 1e-5f);
      float2 o2;
      o2.x = (v0 - mu) * rs * g2v.x + bb2v.x;
      o2.y = (v1 - mu) * rs * g2v.y + bb2v.y;
      *(float2*)(out + (size_t)(pairbase + tl) * 64 + e0) = o2;
    }
  }
}

} // namespace

extern "C" void kernel_launch(void* const* d_in, const int* in_sizes, int n_in,
                              void* d_out, int out_size, void* d_ws, size_t ws_size,
                              hipStream_t stream) {
  (void)in_sizes; (void)n_in; (void)d_ws; (void)ws_size; (void)out_size;
  const float* prec = (const float*)d_in[0];
  const int*   tm   = (const int*)  d_in[1];
  const float* We   = (const float*)d_in[2];
  const float* be   = (const float*)d_in[3];
  const float* Wq   = (const float*)d_in[4];
  const float* Wk   = (const float*)d_in[5];
  const float* Wv   = (const float*)d_in[6];
  const float* Wo   = (const float*)d_in[7];
  const float* bo   = (const float*)d_in[8];
  const float* g1   = (const float*)d_in[9];
  const float* bb1  = (const float*)d_in[10];
  const float* W1   = (const float*)d_in[11];
  const float* b1   = (const float*)d_in[12];
  const float* W2   = (const float*)d_in[13];
  const float* b2   = (const float*)d_in[14];
  const float* g2   = (const float*)d_in[15];
  const float* bb2  = (const float*)d_in[16];

  dim3 grid(1536), block(256);
  hipLaunchKernelGGL(prec_fused, grid, block, 0, stream,
                     prec, tm, We, be, Wq, Wk, Wv, Wo, bo, g1, bb1,
                     W1, b1, W2, b2, g2, bb2, (float*)d_out);
}